// Round 9
// baseline (302.365 us; speedup 1.0000x reference)
//
#include <hip/hip_runtime.h>
#include <hip/hip_bf16.h>
#include <cstdint>
#include <cstddef>

#define BATCH 4
#define NPT   8192
#define CH    256
#define KNN   16
#define BN_TOT (BATCH * NPT)   // 32768
#define NSLICE 16              // candidate slices per query (one wave each)
#define SLICE  (NPT / NSLICE)  // 512
#define CAP    32              // candidate cap per (query, slice) in LDS (64 KB)
#define MINI   96              // presample per wave (1536 samples/query total)

typedef __attribute__((ext_vector_type(8))) short bf16x8;
typedef __attribute__((ext_vector_type(4))) float f32x4;
typedef __attribute__((ext_vector_type(8))) float f32x8;
typedef __attribute__((ext_vector_type(16))) float f32x16;

// np-matching f32 distance (DO NOT CHANGE — verified in R4):
//   dot: numpy einsum scalar tail (count=3), ascending FMA chain;
//   then separate ufuncs: t = round(-2*dot); t = t + sn; t = t + sm.
__device__ __forceinline__ float dist2np(const float4 qp, const float4 cp) {
#pragma clang fp contract(off)
  float acc = qp.x * cp.x;                    // == fmaf(x,x',0)
  acc = __builtin_fmaf(qp.y, cp.y, acc);
  acc = __builtin_fmaf(qp.z, cp.z, acc);
  float t = -2.0f * acc;
  t = t + qp.w;
  t = t + cp.w;
  return t;
}

__device__ __forceinline__ unsigned int pk_bf16(float a, float b) {
  __hip_bfloat162 h = __float22bfloat162_rn(make_float2(a, b));
  return *(unsigned int*)&h;
}

// packed fast-d for 8 candidates from ONE contiguous 128B blocked-SoA block
// [x0..7][y0..7][z0..7][w0..7]: 2x uniform 64B loads (single-stream sequential
// s_load pattern, R6/R8-proven) + v_pk_*_f32 math (2 cands/inst; SAME IEEE ops
// in SAME order as scalar chain -> bit-identical fast-d, R5-verified).
// 4-stream SoA is BLACKLISTED (R7: 1.5GB HBM explosion).
__device__ __forceinline__ f32x8 dist8(
    float qw, float m2x, float m2y, float m2z,
    const f32x16* __restrict__ cs, int j)
{
  f32x16 lo = cs[2 * j];       // x0..7, y0..7
  f32x16 hi = cs[2 * j + 1];   // z0..7, w0..7
  f32x8 cx = __builtin_shufflevector(lo, lo, 0, 1, 2, 3, 4, 5, 6, 7);
  f32x8 cy = __builtin_shufflevector(lo, lo, 8, 9, 10, 11, 12, 13, 14, 15);
  f32x8 cz = __builtin_shufflevector(hi, hi, 0, 1, 2, 3, 4, 5, 6, 7);
  f32x8 cw = __builtin_shufflevector(hi, hi, 8, 9, 10, 11, 12, 13, 14, 15);
  f32x8 t = (f32x8)qw + cw;
  t = __builtin_elementwise_fma((f32x8)m2x, cx, t);
  t = __builtin_elementwise_fma((f32x8)m2y, cy, t);
  t = __builtin_elementwise_fma((f32x8)m2z, cz, t);
  return t;
}

// ---------------- prep: cpack AoS + cblk blocked-SoA + WbT + optional Q16
__global__ __launch_bounds__(256) void prep_kernel(
    const float* __restrict__ q_pos, const float* __restrict__ W,
    float4* __restrict__ cpack, float* __restrict__ cblk,
    unsigned short* __restrict__ WbT,
    const float* __restrict__ Q, unsigned short* __restrict__ Q16)
{
  int t = blockIdx.x * 256 + threadIdx.x;   // 0..131071
  {
    int k = t >> 9;
    int j = t & 511;
    float v;
    if (j < 256) {
      v = W[k * 256 + j];
    } else {
      int c = j - 256;
      v = W[(256 + k) * 256 + c] - W[k * 256 + c];
    }
    __hip_bfloat16 hb = __float2bfloat16(v);       // RNE
    WbT[(size_t)j * 256 + k] = *(unsigned short*)&hb;
  }
  if (t < BN_TOT) {
#pragma clang fp contract(off)
    float x = q_pos[3 * t + 0];
    float y = q_pos[3 * t + 1];
    float z = q_pos[3 * t + 2];
    float pxx = x * x;
    float pyy = y * y;
    float pzz = z * z;
    float s = pxx + pyy;
    s = s + pzz;
    cpack[t] = make_float4(x, y, z, s);
    // blocked-SoA: block (t>>3) holds [x0..7][y0..7][z0..7][w0..7]
    float* cb = cblk + ((size_t)(t >> 3) << 5) + (t & 7);
    cb[0] = x; cb[8] = y; cb[16] = z; cb[24] = s;
  }
  if (Q16) {   // bf16 copy of Q (RNE, identical to the in-gemm pk_bf16 path)
    const float4* __restrict__ qs = (const float4*)Q;
    uint2* __restrict__ qd = (uint2*)Q16;
#pragma unroll 4
    for (int i = t; i < BN_TOT * 64; i += 131072) {
      float4 f = qs[i];
      qd[i] = make_uint2(pk_bf16(f.x, f.y), pk_bf16(f.z, f.w));
    }
  }
}

// ---------------- knn (2-pass fused): presample hist (MINI=96) -> loose edge U
// -> ONE collect-only full pass under edge(U) (R4-proven: exact phase-3
// selection over the loose superset == tight-set selection, since the
// verified tight set contains all np-d<=T and loose extras all fail d<T/d==T)
// -> rare per-slice CAP overflow: exact redo (predicated hist -> tight edge ->
// re-collect, the R5/R7-proven configuration) -> 4-wave partial top-16 ->
// wave-0 merge. 1024-thr blocks: 64 queries (lane), 16 waves = 16 slices.
__global__ __launch_bounds__(1024, 8) void knn_kernel(
    const float4* __restrict__ cpack, const float* __restrict__ cblk,
    int* __restrict__ idxout)
{
  __shared__ __align__(16) unsigned short cand[NSLICE * 64 * CAP]; // 64 KB; group-g region reused for (d,idx) lists
  __shared__ unsigned int hist[32][64];              // 8 KB bank-transposed shared hist
  __shared__ unsigned short scnt[NSLICE][64];        // per (slice,query) RAW candidate count (<=512 fits u16)
  __shared__ float edge_s[64];                       // tight edge (redo path only)
  __shared__ int ubnd[64];                           // per-query raw-bin upper bound (241+Bm)
  __shared__ int ovf_s[64];                          // per-query overflow flag
  __shared__ int anyovf;                             // block-wide overflow flag

  const int tid = threadIdx.x;
  const int l   = tid & 63;                        // query lane
  const int w   = __builtin_amdgcn_readfirstlane(tid >> 6);  // slice (wave-uniform)
  const int b   = blockIdx.y;
  const int q   = b * NPT + blockIdx.x * 64 + l;

  // zero shared histogram (2048 dwords / 1024 threads) + flags
  ((unsigned int*)hist)[tid] = 0u;
  ((unsigned int*)hist)[tid + 1024] = 0u;
  if (tid == 0) anyovf = 0;
  __syncthreads();

  const float4 qp = cpack[q];
  const float m2x = -2.0f * qp.x, m2y = -2.0f * qp.y, m2z = -2.0f * qp.z;
  const float4* __restrict__ cb = cpack + b * NPT;
  const f32x16* __restrict__ cs = (const f32x16*)(cblk + (size_t)b * NPT * 4);
  const int j0 = (w * SLICE) >> 3;                 // 64 blocks of 8 per slice
  // hist row for raw-clamped bin r in [241,272]: fold -241 into the base.
  unsigned int* hb = (unsigned int*)((char*)&hist[0][0] - (241 << 8)) + l;

  // pass A (presample): first MINI candidates per slice, unpredicated atomics.
#pragma unroll 1
  for (int j = j0; j < j0 + MINI / 8; ++j) {
    f32x8 t = dist8(qp.w, m2x, m2y, m2z, cs, j);
#pragma unroll
    for (int u = 0; u < 8; ++u) {
      int r = __float_as_int(t[u]) >> 22;          // arith shift: d<=0 -> 241 after clamp
      r = min(max(r, 241), 272);
      atomicAdd(hb + (r << 6), 1u);                // bank = l&31: conflict-free
    }
  }
  __syncthreads();

  // per-query loose bound: Bm = bin of 16th smallest of the 1536 samples.
  // sample subset of population => cum_full(Bm) >= 16 => true tight B* <= Bm.
  if (tid < 64) {
    int cum = 0, Bm = 31;
#pragma unroll 1
    for (int bb = 0; bb < 32; ++bb) {
      cum += (int)hist[bb][tid];
      if (cum >= KNN) { Bm = bb; break; }
    }
    ubnd[tid] = 241 + Bm;
  }
  __syncthreads();

  // pass B (full slice): collect candidates with d < edge(U) into LDS
  // (ascending m; branch body identical to the R6/R8-proven scan2 body —
  // no histogram atomics here, the R4 if-conversion trap).
  const int ub = ubnd[l];
  const float ubEdgef = __uint_as_float((unsigned)(ub + 1) << 22);
  unsigned int cnt = 0;
  unsigned short* mybuf = &cand[(w * 64 + l) * CAP];
#pragma unroll 1
  for (int j = j0; j < j0 + SLICE / 8; ++j) {
    f32x8 t = dist8(qp.w, m2x, m2y, m2z, cs, j);
#pragma unroll
    for (int u = 0; u < 8; ++u) {
      if (t[u] < ubEdgef) {                        // ~2% lanes active
        if (cnt < CAP) mybuf[cnt] = (unsigned short)((j << 3) + u);
        cnt++;
      }
    }
  }
  scnt[w][l] = (unsigned short)cnt;                // RAW count (overflow detect)
  __syncthreads();

  // overflow detect: any (slice,query) with loose-edge count > CAP?
  if (tid < 64) {
    int o = 0;
#pragma unroll
    for (int w2 = 0; w2 < NSLICE; ++w2) o |= (int)(scnt[w2][tid] > CAP);
    ovf_s[tid] = o;
    if (o) anyovf = 1;
  }
  __syncthreads();

  if (anyovf) {   // block-uniform branch; rare (loose edge ~9-14 cands/slice avg)
    // zero hist columns of overflowed queries
    if (tid < 64 && ovf_s[tid]) {
#pragma unroll 1
      for (int bb = 0; bb < 32; ++bb) hist[bb][tid] = 0u;
    }
    __syncthreads();
    // exact predicated histogram over the full slice for overflowed lanes
    const int lo = ovf_s[l];
#pragma unroll 1
    for (int j = j0; j < j0 + SLICE / 8; ++j) {
      f32x8 t = dist8(qp.w, m2x, m2y, m2z, cs, j);
#pragma unroll
      for (int u = 0; u < 8; ++u) {
        if (lo && t[u] < ubEdgef) {
          int r = max(__float_as_int(t[u]) >> 22, 241);
          atomicAdd(hb + (r << 6), 1u);
        }
      }
    }
    __syncthreads();
    // tight edge: bins <= ub exact -> cumsum stops at B* <= ub (R5/R7-proven)
    if (tid < 64 && ovf_s[tid]) {
      int cum = 0, B = 31;
#pragma unroll 1
      for (int bb = 0; bb < 32; ++bb) {
        cum += (int)hist[bb][tid];
        if (cum >= KNN) { B = bb; break; }
      }
      edge_s[tid] = __uint_as_float((unsigned)(242 + B) << 22);
    }
    __syncthreads();
    // re-collect with the tight edge for overflowed lanes
    if (ovf_s[l]) {
      const float edgef = edge_s[l];
      cnt = 0;
#pragma unroll 1
      for (int j = j0; j < j0 + SLICE / 8; ++j) {
        f32x8 t = dist8(qp.w, m2x, m2y, m2z, cs, j);
#pragma unroll
        for (int u = 0; u < 8; ++u) {
          if (t[u] < edgef) {
            if (cnt < CAP) mybuf[cnt] = (unsigned short)((j << 3) + u);
            cnt++;
          }
        }
      }
      scnt[w][l] = (unsigned short)cnt;
    }
    __syncthreads();
  }

  // phase 3a: 4 groups (waves 0-3), group g owns slices [4g,4g+4).
  // Each lane (=query) builds an index-carrying sorted top-16 over its group's
  // candidates (stable insertion: ties keep earliest arrival = earliest index,
  // since slices and within-slice candidates ascend). Exact dist2np selection
  // over the loose-edge superset == tight-set selection (R4-verified logic).
  if ((tid >> 6) < 4) {
    const int g = tid >> 6;
    const int nself = (q & (NPT - 1));
    float rd[16]; int ri[16];
#pragma unroll
    for (int j = 0; j < 16; ++j) { rd[j] = __builtin_inff(); ri[j] = nself; }
#pragma unroll 1
    for (int w2 = 4 * g; w2 < 4 * g + 4; ++w2) {
      int cw = (int)scnt[w2][l];
      cw = cw < CAP ? cw : CAP;
      for (int i = 0; i < cw; ++i) {
        int m = (int)cand[(w2 * 64 + l) * CAP + i];
        float d = dist2np(qp, cb[m]);
        if (d < rd[15]) {
          // insert at first j with d < rd[j] (strict: after equals = stable)
#pragma unroll
          for (int j = 15; j > 0; --j) {
            bool up = d < rd[j - 1];
            float nd = up ? rd[j - 1] : d;
            int   ni = up ? ri[j - 1] : m;
            if (d < rd[j]) { rd[j] = nd; ri[j] = ni; }
          }
          if (d < rd[0]) { rd[0] = d; ri[0] = m; }
        }
      }
    }
    float2* pls = (float2*)(cand + (size_t)g * 8192);   // 64q x 16 x 8B = 8KB of the 16KB region
#pragma unroll
    for (int j = 0; j < 16; ++j) {
      int pos = (j + l) & 15;                            // lane swizzle: spread banks
      pls[l * 16 + pos] = make_float2(rd[j], __int_as_float(ri[j]));
    }
  }
  __syncthreads();

  // phase 3b (wave 0, lane = query): 4-way merge of sorted lists, 16 steps.
  // Strict < keeps lowest group on ties => earliest global index (groups are
  // ascending slice ranges). +inf padding carries nself => default semantics.
  if (tid < 64) {
    const float2* pls0 = (const float2*)(cand);
    const float2* pls1 = (const float2*)(cand + 8192);
    const float2* pls2 = (const float2*)(cand + 16384);
    const float2* pls3 = (const float2*)(cand + 24576);
    int p0 = 0, p1 = 0, p2 = 0, p3 = 0;
    float2 h0 = pls0[l * 16 + (l & 15)];
    float2 h1 = pls1[l * 16 + (l & 15)];
    float2 h2 = pls2[l * 16 + (l & 15)];
    float2 h3 = pls3[l * 16 + (l & 15)];
#pragma unroll 1
    for (int s = 0; s < 16; ++s) {
      float bd = h0.x; int be = __float_as_int(h0.y); int bg = 0;
      if (h1.x < bd) { bd = h1.x; be = __float_as_int(h1.y); bg = 1; }
      if (h2.x < bd) { bd = h2.x; be = __float_as_int(h2.y); bg = 2; }
      if (h3.x < bd) { bd = h3.x; be = __float_as_int(h3.y); bg = 3; }
      idxout[(size_t)q * 16 + s] = be;
      p0 += (bg == 0); p1 += (bg == 1); p2 += (bg == 2); p3 += (bg == 3);
      int q0 = p0 < 16 ? p0 : 15;   // clamp: final (dead) reload stays in-bounds
      int q1 = p1 < 16 ? p1 : 15;
      int q2 = p2 < 16 ? p2 : 15;
      int q3 = p3 < 16 ? p3 : 15;
      h0 = pls0[l * 16 + ((q0 + l) & 15)];
      h1 = pls1[l * 16 + ((q1 + l) & 15)];
      h2 = pls2[l * 16 + ((q2 + l) & 15)];
      h3 = pls3[l * 16 + ((q3 + l) & 15)];
    }
  }
}

// ---------------- bf16 MFMA GEMM: Q[32768,256] x WbT[512,256]^T -> A16 bf16 (n<256), Qn=d_out f32 (n>=256,+bias)
// USEQ16: A-side staged from pre-converted bf16 Q16 (2 uint4 loads, no VALU
// conversion); else f32 loads + in-loop pk_bf16 (identical RNE values).
#define ASTRIDE 40   // LDS row stride in bf16 elems (80 B, 16B-aligned)
template<bool USEQ16>
__global__ __launch_bounds__(256) void gemm_kernel(
    const float* __restrict__ Q, const unsigned short* __restrict__ Q16,
    const unsigned short* __restrict__ WbT,
    const float* __restrict__ bias,
    unsigned short* __restrict__ A16, float* __restrict__ Qn)
{
  __shared__ __align__(16) unsigned short As[128 * ASTRIDE];
  __shared__ __align__(16) unsigned short Bs[128 * ASTRIDE];
  const int tid  = threadIdx.x;
  const int lane = tid & 63;
  const int wv   = tid >> 6;
  const int wr   = wv & 1, wc = wv >> 1;
  const int bid  = blockIdx.x;
  const int bm0  = (bid >> 2) * 128;
  const int bn0  = (bid & 3) * 128;
  const int srow = tid >> 1;
  const int skh  = tid & 1;
  const int quad = lane >> 4;
  const int l15  = lane & 15;

  f32x4 acc[4][4];
#pragma unroll
  for (int i = 0; i < 4; ++i)
#pragma unroll
    for (int j = 0; j < 4; ++j) acc[i][j] = (f32x4)0.0f;

  const float* ag = Q + (size_t)(bm0 + srow) * 256 + skh * 16;
  const unsigned short* ag16 = USEQ16 ? (Q16 + (size_t)(bm0 + srow) * 256 + skh * 16) : nullptr;
  const unsigned short* bg = WbT + (size_t)(bn0 + srow) * 256 + skh * 16;
  unsigned short* asw = &As[srow * ASTRIDE + skh * 16];
  unsigned short* bsw = &Bs[srow * ASTRIDE + skh * 16];

  for (int k0 = 0; k0 < 256; k0 += 32) {
    uint4 a0, a1;
    if constexpr (USEQ16) {
      a0 = *(const uint4*)(ag16 + k0);
      a1 = *(const uint4*)(ag16 + k0 + 8);
    } else {
      float4 f0 = *(const float4*)(ag + k0);
      float4 f1 = *(const float4*)(ag + k0 + 4);
      float4 f2 = *(const float4*)(ag + k0 + 8);
      float4 f3 = *(const float4*)(ag + k0 + 12);
      a0.x = pk_bf16(f0.x, f0.y); a0.y = pk_bf16(f0.z, f0.w);
      a0.z = pk_bf16(f1.x, f1.y); a0.w = pk_bf16(f1.z, f1.w);
      a1.x = pk_bf16(f2.x, f2.y); a1.y = pk_bf16(f2.z, f2.w);
      a1.z = pk_bf16(f3.x, f3.y); a1.w = pk_bf16(f3.z, f3.w);
    }
    uint4 bv0 = *(const uint4*)(bg + k0);        // k-local [0,8)
    uint4 bv1 = *(const uint4*)(bg + k0 + 8);    // k-local [8,16)
    __syncthreads();
    *(uint4*)(asw) = a0;
    *(uint4*)(asw + 8) = a1;
    *(uint4*)(bsw) = bv0;
    *(uint4*)(bsw + 8) = bv1;
    __syncthreads();

    bf16x8 af[4], bf[4];
#pragma unroll
    for (int rt = 0; rt < 4; ++rt)
      af[rt] = *(const bf16x8*)&As[(wr * 64 + rt * 16 + l15) * ASTRIDE + quad * 8];
#pragma unroll
    for (int ct = 0; ct < 4; ++ct)
      bf[ct] = *(const bf16x8*)&Bs[(wc * 64 + ct * 16 + l15) * ASTRIDE + quad * 8];
#pragma unroll
    for (int rt = 0; rt < 4; ++rt)
#pragma unroll
      for (int ct = 0; ct < 4; ++ct)
        acc[rt][ct] = __builtin_amdgcn_mfma_f32_16x16x32_bf16(af[rt], bf[ct], acc[rt][ct], 0, 0, 0);
  }

  // epilogue: C/D layout col=lane&15, row=quad*4+reg (verified m89/m91)
  if (bn0 < 256) {
#pragma unroll
    for (int ct = 0; ct < 4; ++ct) {
      int col = bn0 + wc * 64 + ct * 16 + l15;
#pragma unroll
      for (int rt = 0; rt < 4; ++rt) {
        int rowb = bm0 + wr * 64 + rt * 16 + quad * 4;
#pragma unroll
        for (int r = 0; r < 4; ++r) {
          __hip_bfloat16 hb = __float2bfloat16(acc[rt][ct][r]);
          A16[(size_t)(rowb + r) * 256 + col] = *(unsigned short*)&hb;
        }
      }
    }
  } else {
#pragma unroll
    for (int ct = 0; ct < 4; ++ct) {
      int col = bn0 + wc * 64 + ct * 16 + l15 - 256;
      float bvl = bias[col];
#pragma unroll
      for (int rt = 0; rt < 4; ++rt) {
        int rowb = bm0 + wr * 64 + rt * 16 + quad * 4;
#pragma unroll
        for (int r = 0; r < 4; ++r)
          Qn[(size_t)(rowb + r) * 256 + col] = acc[rt][ct][r] + bvl;
      }
    }
  }
}

// ---------------- gather + leaky + max; Out holds Qn on entry, overwritten with result
// 4 queries/block, 64 lanes/query, 4 channels/lane: one neighbor row (512 B)
// per wave-instruction via ushort4 (was 2 B/lane = 128 B/instr).
__global__ __launch_bounds__(256) void gather_kernel(
    const unsigned short* __restrict__ A16, const int* __restrict__ idxout,
    float* __restrict__ Out)
{
  __shared__ int sidx[64];
  const int tid  = threadIdx.x;
  const int q0   = blockIdx.x * 4;
  const int sub  = tid >> 6;
  const int lane = tid & 63;
  const int q    = q0 + sub;
  const int b    = q >> 13;
  if (tid < 64) sidx[tid] = idxout[(size_t)q0 * 16 + tid];
  __syncthreads();
  const int c4 = lane * 4;
  float* op = Out + (size_t)q * 256 + c4;
  const float4 qn = *(const float4*)op;
  const unsigned short* __restrict__ Ab = A16 + (size_t)b * NPT * 256 + c4;
  const float NI = -__builtin_inff();
  float4 best = make_float4(NI, NI, NI, NI);
#pragma unroll
  for (int j = 0; j < 16; ++j) {
    const ushort4 raw = *(const ushort4*)(Ab + (size_t)sidx[sub * 16 + j] * 256);
    float4 h;
    h.x = __uint_as_float((unsigned)raw.x << 16) + qn.x;   // bf16 -> f32
    h.y = __uint_as_float((unsigned)raw.y << 16) + qn.y;
    h.z = __uint_as_float((unsigned)raw.z << 16) + qn.z;
    h.w = __uint_as_float((unsigned)raw.w << 16) + qn.w;
    best.x = fmaxf(best.x, fmaxf(h.x, 0.2f * h.x));        // leaky_relu(h,0.2)
    best.y = fmaxf(best.y, fmaxf(h.y, 0.2f * h.y));
    best.z = fmaxf(best.z, fmaxf(h.z, 0.2f * h.z));
    best.w = fmaxf(best.w, fmaxf(h.w, 0.2f * h.w));
  }
  *(float4*)op = best;
}

extern "C" void kernel_launch(void* const* d_in, const int* in_sizes, int n_in,
                              void* d_out, int out_size, void* d_ws, size_t ws_size,
                              hipStream_t stream)
{
  (void)in_sizes; (void)n_in; (void)out_size;
  const float* qf   = (const float*)d_in[0];
  const float* qpos = (const float*)d_in[1];
  const float* W    = (const float*)d_in[2];
  const float* bias = (const float*)d_in[3];

  char* ws = (char*)d_ws;
  size_t off = 0;
  auto alloc = [&](size_t bytes) {
    void* p = ws + off;
    off += (bytes + 255) & ~(size_t)255;
    return p;
  };
  float4* cpack       = (float4*)alloc((size_t)BN_TOT * sizeof(float4));       // 512 KB
  float* cblk         = (float*)alloc((size_t)BN_TOT * 4 * sizeof(float));     // 512 KB blocked-SoA
  unsigned short* WbT = (unsigned short*)alloc((size_t)512 * 256 * 2);         // 256 KB
  int* idxout         = (int*)alloc((size_t)BN_TOT * KNN * sizeof(int));       // 2 MB
  unsigned short* A16 = (unsigned short*)alloc((size_t)BN_TOT * CH * 2);       // 16 MB
  float* Out          = (float*)d_out;                                         // Qn then result

  // optional bf16 Q (gemm A-side prestage) — gated on workspace headroom
  unsigned short* Q16 = nullptr;
  if (ws_size >= off + (size_t)BN_TOT * CH * 2 + 256)
    Q16 = (unsigned short*)alloc((size_t)BN_TOT * CH * 2);                     // 16 MB

  prep_kernel<<<512, 256, 0, stream>>>(qpos, W, cpack, cblk, WbT, qf, Q16);
  knn_kernel<<<dim3(128, BATCH), 1024, 0, stream>>>(cpack, cblk, idxout);
  if (Q16)
    gemm_kernel<true><<<1024, 256, 0, stream>>>(qf, Q16, WbT, bias, A16, Out);
  else
    gemm_kernel<false><<<1024, 256, 0, stream>>>(qf, nullptr, WbT, bias, A16, Out);
  gather_kernel<<<BN_TOT / 4, 256, 0, stream>>>(A16, idxout, Out);
}

// Round 10
// 250.284 us; speedup vs baseline: 1.2081x; 1.2081x over previous
//
#include <hip/hip_runtime.h>
#include <hip/hip_bf16.h>
#include <cstdint>
#include <cstddef>

#define BATCH 4
#define NPT   8192
#define CH    256
#define KNN   16
#define BN_TOT (BATCH * NPT)   // 32768
#define NSLICE 16              // candidate slices per query (one wave each)
#define SLICE  (NPT / NSLICE)  // 512
#define CAP    32              // candidate cap per (query, slice) in LDS (64 KB)
#define MINI   32              // scan-1 presample per wave (512 samples/query total)

typedef __attribute__((ext_vector_type(8))) short bf16x8;
typedef __attribute__((ext_vector_type(4))) float f32x4;
typedef __attribute__((ext_vector_type(8))) float f32x8;
typedef __attribute__((ext_vector_type(16))) float f32x16;

// np-matching f32 distance (DO NOT CHANGE — verified in R4):
//   dot: numpy einsum scalar tail (count=3), ascending FMA chain;
//   then separate ufuncs: t = round(-2*dot); t = t + sn; t = t + sm.
__device__ __forceinline__ float dist2np(const float4 qp, const float4 cp) {
#pragma clang fp contract(off)
  float acc = qp.x * cp.x;                    // == fmaf(x,x',0)
  acc = __builtin_fmaf(qp.y, cp.y, acc);
  acc = __builtin_fmaf(qp.z, cp.z, acc);
  float t = -2.0f * acc;
  t = t + qp.w;
  t = t + cp.w;
  return t;
}

__device__ __forceinline__ unsigned int pk_bf16(float a, float b) {
  __hip_bfloat162 h = __float22bfloat162_rn(make_float2(a, b));
  return *(unsigned int*)&h;
}

// packed fast-d for 8 candidates from ONE contiguous 128B blocked-SoA block
// [x0..7][y0..7][z0..7][w0..7]: 2x uniform 64B loads (single-stream sequential
// s_load pattern, R6/R8-proven) + v_pk_*_f32 math (2 cands/inst; SAME IEEE ops
// in SAME order as scalar chain -> bit-identical fast-d, R5-verified).
// 4-stream SoA is BLACKLISTED (R7: 1.5GB HBM explosion). Per-query overflow
// fallbacks are BLACKLISTED (R9: lane=query layout makes them block-wide).
__device__ __forceinline__ f32x8 dist8(
    float qw, float m2x, float m2y, float m2z,
    const f32x16* __restrict__ cs, int j)
{
  f32x16 lo = cs[2 * j];       // x0..7, y0..7
  f32x16 hi = cs[2 * j + 1];   // z0..7, w0..7
  f32x8 cx = __builtin_shufflevector(lo, lo, 0, 1, 2, 3, 4, 5, 6, 7);
  f32x8 cy = __builtin_shufflevector(lo, lo, 8, 9, 10, 11, 12, 13, 14, 15);
  f32x8 cz = __builtin_shufflevector(hi, hi, 0, 1, 2, 3, 4, 5, 6, 7);
  f32x8 cw = __builtin_shufflevector(hi, hi, 8, 9, 10, 11, 12, 13, 14, 15);
  f32x8 t = (f32x8)qw + cw;
  t = __builtin_elementwise_fma((f32x8)m2x, cx, t);
  t = __builtin_elementwise_fma((f32x8)m2y, cy, t);
  t = __builtin_elementwise_fma((f32x8)m2z, cz, t);
  return t;
}

// ---------------- prep: cpack AoS + cblk blocked-SoA + WbT + optional Q16
__global__ __launch_bounds__(256) void prep_kernel(
    const float* __restrict__ q_pos, const float* __restrict__ W,
    float4* __restrict__ cpack, float* __restrict__ cblk,
    unsigned short* __restrict__ WbT,
    const float* __restrict__ Q, unsigned short* __restrict__ Q16)
{
  int t = blockIdx.x * 256 + threadIdx.x;   // 0..131071
  {
    int k = t >> 9;
    int j = t & 511;
    float v;
    if (j < 256) {
      v = W[k * 256 + j];
    } else {
      int c = j - 256;
      v = W[(256 + k) * 256 + c] - W[k * 256 + c];
    }
    __hip_bfloat16 hb = __float2bfloat16(v);       // RNE
    WbT[(size_t)j * 256 + k] = *(unsigned short*)&hb;
  }
  if (t < BN_TOT) {
#pragma clang fp contract(off)
    float x = q_pos[3 * t + 0];
    float y = q_pos[3 * t + 1];
    float z = q_pos[3 * t + 2];
    float pxx = x * x;
    float pyy = y * y;
    float pzz = z * z;
    float s = pxx + pyy;
    s = s + pzz;
    cpack[t] = make_float4(x, y, z, s);
    // blocked-SoA: block (t>>3) holds [x0..7][y0..7][z0..7][w0..7]
    float* cb = cblk + ((size_t)(t >> 3) << 5) + (t & 7);
    cb[0] = x; cb[8] = y; cb[16] = z; cb[24] = s;
  }
  if (Q16) {   // bf16 copy of Q (RNE, identical to the in-gemm pk_bf16 path)
    const float4* __restrict__ qs = (const float4*)Q;
    uint2* __restrict__ qd = (uint2*)Q16;
#pragma unroll 4
    for (int i = t; i < BN_TOT * 64; i += 131072) {
      float4 f = qs[i];
      qd[i] = make_uint2(pk_bf16(f.x, f.y), pk_bf16(f.z, f.w));
    }
  }
}

// ---------------- knn (R8-proven structure, packed scans on blocked-SoA):
// presample hist -> per-query bin upper bound U -> scan1b: hist atomics
// predicated on d<edge(U) (bins<=U exact -> tight edge B* identical) ->
// scan2: collect d<edge into LDS -> 4-wave partial top-16 -> wave-0 merge.
// 1024-thr blocks: 64 queries (lane = query), 16 waves = 16 candidate slices.
__global__ __launch_bounds__(1024, 8) void knn_kernel(
    const float4* __restrict__ cpack, const float* __restrict__ cblk,
    int* __restrict__ idxout)
{
  __shared__ __align__(16) unsigned short cand[NSLICE * 64 * CAP]; // 64 KB; group-g region reused for (d,idx) lists
  __shared__ unsigned int hist[32][64];              // 8 KB bank-transposed shared hist
  __shared__ unsigned short scnt[NSLICE][64];        // per (slice,query) candidate count (2 KB)
  __shared__ float edge_s[64];
  __shared__ int ubnd[64];                           // per-query raw-bin upper bound (241+Bm)

  const int tid = threadIdx.x;
  const int l   = tid & 63;                        // query lane
  const int w   = __builtin_amdgcn_readfirstlane(tid >> 6);  // slice (wave-uniform)
  const int b   = blockIdx.y;
  const int q   = b * NPT + blockIdx.x * 64 + l;

  // zero shared histogram (2048 dwords / 1024 threads)
  ((unsigned int*)hist)[tid] = 0u;
  ((unsigned int*)hist)[tid + 1024] = 0u;
  __syncthreads();

  const float4 qp = cpack[q];
  const float m2x = -2.0f * qp.x, m2y = -2.0f * qp.y, m2z = -2.0f * qp.z;
  const float4* __restrict__ cb = cpack + b * NPT;
  const f32x16* __restrict__ cs = (const f32x16*)(cblk + (size_t)b * NPT * 4);
  const int j0 = (w * SLICE) >> 3;                 // 64 blocks of 8 per slice
  // hist row for raw-clamped bin r in [241,272]: fold -241 into the base.
  unsigned int* hb = (unsigned int*)((char*)&hist[0][0] - (241 << 8)) + l;

  // scan 1a (presample): first MINI candidates per slice, unpredicated atomics.
#pragma unroll 1
  for (int j = j0; j < j0 + MINI / 8; ++j) {
    f32x8 t = dist8(qp.w, m2x, m2y, m2z, cs, j);
#pragma unroll
    for (int u = 0; u < 8; ++u) {
      int r = __float_as_int(t[u]) >> 22;          // arith shift: d<=0 -> 241 after clamp
      r = min(max(r, 241), 272);
      atomicAdd(hb + (r << 6), 1u);                // bank = l&31: conflict-free
    }
  }
  __syncthreads();

  // per-query upper bound: Bm = bin of 16th smallest of the 512 samples.
  // sample subset of population => cum_full(Bm) >= 16 => true tight B* <= Bm.
  if (tid < 64) {
    int cum = 0, Bm = 31;
#pragma unroll 1
    for (int bb = 0; bb < 32; ++bb) {
      cum += (int)hist[bb][tid];
      if (cum >= KNN) { Bm = bb; break; }
    }
    ubnd[tid] = 241 + Bm;
  }
  __syncthreads();

  // scan 1b (rest of slice): atomics predicated on d < upper-edge(U).
  // (bin(d) <= U  <=>  d < edge(U): float bit-pattern monotone for d>=0;
  //  d<0 passes the compare and max() maps it to bin 241 — both sides agree.
  //  d < edge(U) <= edge(273) also bounds r <= 272, so no upper clamp needed.)
  // Bins <= U receive presample + remainder = EXACT full counts; bins > U are
  // undercounted but never reached by the cumsum (it stops at B* <= U).
  const int ub = ubnd[l];
  const float ubEdgef = __uint_as_float((unsigned)(ub + 1) << 22);
#pragma unroll 1
  for (int j = j0 + MINI / 8; j < j0 + SLICE / 8; ++j) {
    f32x8 t = dist8(qp.w, m2x, m2y, m2z, cs, j);
#pragma unroll
    for (int u = 0; u < 8; ++u) {
      if (t[u] < ubEdgef) {                        // rare
        int r = max(__float_as_int(t[u]) >> 22, 241);
        atomicAdd(hb + (r << 6), 1u);
      }
    }
  }
  __syncthreads();

  // cumsum -> bin B holding the 16th smallest; edge = upper(B) (R5/R7-proven)
  if (tid < 64) {
    int cum = 0, B = 31;
#pragma unroll 1
    for (int bb = 0; bb < 32; ++bb) {
      cum += (int)hist[bb][tid];
      if (cum >= KNN) { B = bb; break; }
    }
    edge_s[tid] = __uint_as_float((unsigned)(242 + B) << 22);
  }
  __syncthreads();

  // scan 2 (full): collect candidates with d < edge into LDS (ascending m)
  const float edgef = edge_s[l];
  unsigned int cnt = 0;
  unsigned short* mybuf = &cand[(w * 64 + l) * CAP];
#pragma unroll 1
  for (int j = j0; j < j0 + SLICE / 8; ++j) {
    f32x8 t = dist8(qp.w, m2x, m2y, m2z, cs, j);
#pragma unroll
    for (int u = 0; u < 8; ++u) {
      if (t[u] < edgef) {
        if (cnt < CAP) mybuf[cnt] = (unsigned short)((j << 3) + u);
        cnt++;
      }
    }
  }
  scnt[w][l] = (unsigned short)(cnt < (unsigned)CAP ? cnt : (unsigned)CAP);
  __syncthreads();

  // phase 3a: 4 groups (waves 0-3), group g owns slices [4g,4g+4).
  // Each lane (=query) builds an index-carrying sorted top-16 over its group's
  // candidates (stable insertion: ties keep earliest arrival = earliest index,
  // since slices and within-slice candidates ascend). Global top-16 is a
  // subset of the union of per-group top-16s. Lists written (d,idx)-packed,
  // lane-swizzled, into the group's own (fully consumed) cand region.
  if ((tid >> 6) < 4) {
    const int g = tid >> 6;
    const int nself = (q & (NPT - 1));
    float rd[16]; int ri[16];
#pragma unroll
    for (int j = 0; j < 16; ++j) { rd[j] = __builtin_inff(); ri[j] = nself; }
#pragma unroll 1
    for (int w2 = 4 * g; w2 < 4 * g + 4; ++w2) {
      int cw = (int)scnt[w2][l];
      for (int i = 0; i < cw; ++i) {
        int m = (int)cand[(w2 * 64 + l) * CAP + i];
        float d = dist2np(qp, cb[m]);
        if (d < rd[15]) {
          // insert at first j with d < rd[j] (strict: after equals = stable)
#pragma unroll
          for (int j = 15; j > 0; --j) {
            bool up = d < rd[j - 1];
            float nd = up ? rd[j - 1] : d;
            int   ni = up ? ri[j - 1] : m;
            if (d < rd[j]) { rd[j] = nd; ri[j] = ni; }
          }
          if (d < rd[0]) { rd[0] = d; ri[0] = m; }
        }
      }
    }
    float2* pls = (float2*)(cand + (size_t)g * 8192);   // 64q x 16 x 8B = 8KB of the 16KB region
#pragma unroll
    for (int j = 0; j < 16; ++j) {
      int pos = (j + l) & 15;                            // lane swizzle: spread banks
      pls[l * 16 + pos] = make_float2(rd[j], __int_as_float(ri[j]));
    }
  }
  __syncthreads();

  // phase 3b (wave 0, lane = query): 4-way merge of sorted lists, 16 steps.
  // Strict < keeps lowest group on ties => earliest global index (groups are
  // ascending slice ranges). +inf padding carries nself => default semantics.
  if (tid < 64) {
    const float2* pls0 = (const float2*)(cand);
    const float2* pls1 = (const float2*)(cand + 8192);
    const float2* pls2 = (const float2*)(cand + 16384);
    const float2* pls3 = (const float2*)(cand + 24576);
    int p0 = 0, p1 = 0, p2 = 0, p3 = 0;
    float2 h0 = pls0[l * 16 + (l & 15)];
    float2 h1 = pls1[l * 16 + (l & 15)];
    float2 h2 = pls2[l * 16 + (l & 15)];
    float2 h3 = pls3[l * 16 + (l & 15)];
#pragma unroll 1
    for (int s = 0; s < 16; ++s) {
      float bd = h0.x; int be = __float_as_int(h0.y); int bg = 0;
      if (h1.x < bd) { bd = h1.x; be = __float_as_int(h1.y); bg = 1; }
      if (h2.x < bd) { bd = h2.x; be = __float_as_int(h2.y); bg = 2; }
      if (h3.x < bd) { bd = h3.x; be = __float_as_int(h3.y); bg = 3; }
      idxout[(size_t)q * 16 + s] = be;
      p0 += (bg == 0); p1 += (bg == 1); p2 += (bg == 2); p3 += (bg == 3);
      int q0 = p0 < 16 ? p0 : 15;   // clamp: final (dead) reload stays in-bounds
      int q1 = p1 < 16 ? p1 : 15;
      int q2 = p2 < 16 ? p2 : 15;
      int q3 = p3 < 16 ? p3 : 15;
      h0 = pls0[l * 16 + ((q0 + l) & 15)];
      h1 = pls1[l * 16 + ((q1 + l) & 15)];
      h2 = pls2[l * 16 + ((q2 + l) & 15)];
      h3 = pls3[l * 16 + ((q3 + l) & 15)];
    }
  }
}

// ---------------- bf16 MFMA GEMM: Q[32768,256] x WbT[512,256]^T -> A16 bf16 (n<256), Qn=d_out f32 (n>=256,+bias)
// Double-buffered LDS ping-pong: ONE barrier per K-step (iter k reads buf[cur],
// writes buf[cur^1]; buf[cur^1]'s readers completed before the previous
// barrier, so a single end-of-iter barrier fences write-after-read), and the
// next tile's global loads issue BEFORE the MFMA cluster (latency hidden).
#define ASTRIDE 40   // LDS row stride in bf16 elems (80 B, 16B-aligned)
template<bool USEQ16>
__global__ __launch_bounds__(256) void gemm_kernel(
    const float* __restrict__ Q, const unsigned short* __restrict__ Q16,
    const unsigned short* __restrict__ WbT,
    const float* __restrict__ bias,
    unsigned short* __restrict__ A16, float* __restrict__ Qn)
{
  __shared__ __align__(16) unsigned short As[2][128 * ASTRIDE];   // 2 x 10 KB
  __shared__ __align__(16) unsigned short Bs[2][128 * ASTRIDE];   // 2 x 10 KB
  const int tid  = threadIdx.x;
  const int lane = tid & 63;
  const int wv   = tid >> 6;
  const int wr   = wv & 1, wc = wv >> 1;
  const int bid  = blockIdx.x;
  const int bm0  = (bid >> 2) * 128;     // grid linearized: 4 N-siblings adjacent
  const int bn0  = (bid & 3) * 128;
  const int srow = tid >> 1;
  const int skh  = tid & 1;
  const int quad = lane >> 4;
  const int l15  = lane & 15;
  const int soff = srow * ASTRIDE + skh * 16;

  f32x4 acc[4][4];
#pragma unroll
  for (int i = 0; i < 4; ++i)
#pragma unroll
    for (int j = 0; j < 4; ++j) acc[i][j] = (f32x4)0.0f;

  const float* ag = Q + (size_t)(bm0 + srow) * 256 + skh * 16;
  const unsigned short* ag16 = USEQ16 ? (Q16 + (size_t)(bm0 + srow) * 256 + skh * 16) : nullptr;
  const unsigned short* bg = WbT + (size_t)(bn0 + srow) * 256 + skh * 16;

  auto loadA = [&](int k0, uint4& a0, uint4& a1) {
    if constexpr (USEQ16) {
      a0 = *(const uint4*)(ag16 + k0);
      a1 = *(const uint4*)(ag16 + k0 + 8);
    } else {
      float4 f0 = *(const float4*)(ag + k0);
      float4 f1 = *(const float4*)(ag + k0 + 4);
      float4 f2 = *(const float4*)(ag + k0 + 8);
      float4 f3 = *(const float4*)(ag + k0 + 12);
      a0.x = pk_bf16(f0.x, f0.y); a0.y = pk_bf16(f0.z, f0.w);
      a0.z = pk_bf16(f1.x, f1.y); a0.w = pk_bf16(f1.z, f1.w);
      a1.x = pk_bf16(f2.x, f2.y); a1.y = pk_bf16(f2.z, f2.w);
      a1.z = pk_bf16(f3.x, f3.y); a1.w = pk_bf16(f3.z, f3.w);
    }
  };

  // prologue: stage tile 0 into buffer 0
  {
    uint4 a0, a1;
    loadA(0, a0, a1);
    uint4 b0 = *(const uint4*)(bg);
    uint4 b1 = *(const uint4*)(bg + 8);
    *(uint4*)&As[0][soff] = a0;
    *(uint4*)&As[0][soff + 8] = a1;
    *(uint4*)&Bs[0][soff] = b0;
    *(uint4*)&Bs[0][soff + 8] = b1;
  }
  __syncthreads();

  int cur = 0;
  for (int k0 = 0; k0 < 256; k0 += 32) {
    const bool more = (k0 + 32) < 256;
    uint4 na0, na1, nb0, nb1;
    if (more) {                         // issue next-tile loads before MFMA
      loadA(k0 + 32, na0, na1);
      nb0 = *(const uint4*)(bg + k0 + 32);
      nb1 = *(const uint4*)(bg + k0 + 40);
    }

    bf16x8 af[4], bf[4];
#pragma unroll
    for (int rt = 0; rt < 4; ++rt)
      af[rt] = *(const bf16x8*)&As[cur][(wr * 64 + rt * 16 + l15) * ASTRIDE + quad * 8];
#pragma unroll
    for (int ct = 0; ct < 4; ++ct)
      bf[ct] = *(const bf16x8*)&Bs[cur][(wc * 64 + ct * 16 + l15) * ASTRIDE + quad * 8];
#pragma unroll
    for (int rt = 0; rt < 4; ++rt)
#pragma unroll
      for (int ct = 0; ct < 4; ++ct)
        acc[rt][ct] = __builtin_amdgcn_mfma_f32_16x16x32_bf16(af[rt], bf[ct], acc[rt][ct], 0, 0, 0);

    if (more) {
      const int nxt = cur ^ 1;
      *(uint4*)&As[nxt][soff] = na0;
      *(uint4*)&As[nxt][soff + 8] = na1;
      *(uint4*)&Bs[nxt][soff] = nb0;
      *(uint4*)&Bs[nxt][soff + 8] = nb1;
      __syncthreads();
      cur = nxt;
    }
  }

  // epilogue: C/D layout col=lane&15, row=quad*4+reg (verified m89/m91)
  if (bn0 < 256) {
#pragma unroll
    for (int ct = 0; ct < 4; ++ct) {
      int col = bn0 + wc * 64 + ct * 16 + l15;
#pragma unroll
      for (int rt = 0; rt < 4; ++rt) {
        int rowb = bm0 + wr * 64 + rt * 16 + quad * 4;
#pragma unroll
        for (int r = 0; r < 4; ++r) {
          __hip_bfloat16 hb = __float2bfloat16(acc[rt][ct][r]);
          A16[(size_t)(rowb + r) * 256 + col] = *(unsigned short*)&hb;
        }
      }
    }
  } else {
#pragma unroll
    for (int ct = 0; ct < 4; ++ct) {
      int col = bn0 + wc * 64 + ct * 16 + l15 - 256;
      float bvl = bias[col];
#pragma unroll
      for (int rt = 0; rt < 4; ++rt) {
        int rowb = bm0 + wr * 64 + rt * 16 + quad * 4;
#pragma unroll
        for (int r = 0; r < 4; ++r)
          Qn[(size_t)(rowb + r) * 256 + col] = acc[rt][ct][r] + bvl;
      }
    }
  }
}

// ---------------- gather + leaky + max; Out holds Qn on entry, overwritten with result
// 4 queries/block, 64 lanes/query, 4 channels/lane: one neighbor row (512 B)
// per wave-instruction via ushort4 (was 2 B/lane = 128 B/instr).
__global__ __launch_bounds__(256) void gather_kernel(
    const unsigned short* __restrict__ A16, const int* __restrict__ idxout,
    float* __restrict__ Out)
{
  __shared__ int sidx[64];
  const int tid  = threadIdx.x;
  const int q0   = blockIdx.x * 4;
  const int sub  = tid >> 6;
  const int lane = tid & 63;
  const int q    = q0 + sub;
  const int b    = q >> 13;
  if (tid < 64) sidx[tid] = idxout[(size_t)q0 * 16 + tid];
  __syncthreads();
  const int c4 = lane * 4;
  float* op = Out + (size_t)q * 256 + c4;
  const float4 qn = *(const float4*)op;
  const unsigned short* __restrict__ Ab = A16 + (size_t)b * NPT * 256 + c4;
  const float NI = -__builtin_inff();
  float4 best = make_float4(NI, NI, NI, NI);
#pragma unroll
  for (int j = 0; j < 16; ++j) {
    const ushort4 raw = *(const ushort4*)(Ab + (size_t)sidx[sub * 16 + j] * 256);
    float4 h;
    h.x = __uint_as_float((unsigned)raw.x << 16) + qn.x;   // bf16 -> f32
    h.y = __uint_as_float((unsigned)raw.y << 16) + qn.y;
    h.z = __uint_as_float((unsigned)raw.z << 16) + qn.z;
    h.w = __uint_as_float((unsigned)raw.w << 16) + qn.w;
    best.x = fmaxf(best.x, fmaxf(h.x, 0.2f * h.x));        // leaky_relu(h,0.2)
    best.y = fmaxf(best.y, fmaxf(h.y, 0.2f * h.y));
    best.z = fmaxf(best.z, fmaxf(h.z, 0.2f * h.z));
    best.w = fmaxf(best.w, fmaxf(h.w, 0.2f * h.w));
  }
  *(float4*)op = best;
}

extern "C" void kernel_launch(void* const* d_in, const int* in_sizes, int n_in,
                              void* d_out, int out_size, void* d_ws, size_t ws_size,
                              hipStream_t stream)
{
  (void)in_sizes; (void)n_in; (void)out_size;
  const float* qf   = (const float*)d_in[0];
  const float* qpos = (const float*)d_in[1];
  const float* W    = (const float*)d_in[2];
  const float* bias = (const float*)d_in[3];

  char* ws = (char*)d_ws;
  size_t off = 0;
  auto alloc = [&](size_t bytes) {
    void* p = ws + off;
    off += (bytes + 255) & ~(size_t)255;
    return p;
  };
  float4* cpack       = (float4*)alloc((size_t)BN_TOT * sizeof(float4));       // 512 KB
  float* cblk         = (float*)alloc((size_t)BN_TOT * 4 * sizeof(float));     // 512 KB blocked-SoA
  unsigned short* WbT = (unsigned short*)alloc((size_t)512 * 256 * 2);         // 256 KB
  int* idxout         = (int*)alloc((size_t)BN_TOT * KNN * sizeof(int));       // 2 MB
  unsigned short* A16 = (unsigned short*)alloc((size_t)BN_TOT * CH * 2);       // 16 MB
  float* Out          = (float*)d_out;                                         // Qn then result

  // optional bf16 Q (gemm A-side prestage) — gated on workspace headroom
  unsigned short* Q16 = nullptr;
  if (ws_size >= off + (size_t)BN_TOT * CH * 2 + 256)
    Q16 = (unsigned short*)alloc((size_t)BN_TOT * CH * 2);                     // 16 MB

  prep_kernel<<<512, 256, 0, stream>>>(qpos, W, cpack, cblk, WbT, qf, Q16);
  knn_kernel<<<dim3(128, BATCH), 1024, 0, stream>>>(cpack, cblk, idxout);
  if (Q16)
    gemm_kernel<true><<<1024, 256, 0, stream>>>(qf, Q16, WbT, bias, A16, Out);
  else
    gemm_kernel<false><<<1024, 256, 0, stream>>>(qf, nullptr, WbT, bias, A16, Out);
  gather_kernel<<<BN_TOT / 4, 256, 0, stream>>>(A16, idxout, Out);
}

// Round 11
// 247.633 us; speedup vs baseline: 1.2210x; 1.0107x over previous
//
#include <hip/hip_runtime.h>
#include <hip/hip_bf16.h>
#include <cstdint>
#include <cstddef>

#define BATCH 4
#define NPT   8192
#define CH    256
#define KNN   16
#define BN_TOT (BATCH * NPT)   // 32768
#define NSLICE 16              // candidate slices per query (one wave each)
#define SLICE  (NPT / NSLICE)  // 512
#define CAP    32              // candidate cap per (query, slice) in LDS (64 KB)
#define MINI   32              // scan-1 presample per wave (512 samples/query total)

typedef __attribute__((ext_vector_type(8))) short bf16x8;
typedef __attribute__((ext_vector_type(4))) float f32x4;
typedef __attribute__((ext_vector_type(8))) float f32x8;
typedef __attribute__((ext_vector_type(16))) float f32x16;

// np-matching f32 distance (DO NOT CHANGE — verified in R4):
//   dot: numpy einsum scalar tail (count=3), ascending FMA chain;
//   then separate ufuncs: t = round(-2*dot); t = t + sn; t = t + sm.
__device__ __forceinline__ float dist2np(const float4 qp, const float4 cp) {
#pragma clang fp contract(off)
  float acc = qp.x * cp.x;                    // == fmaf(x,x',0)
  acc = __builtin_fmaf(qp.y, cp.y, acc);
  acc = __builtin_fmaf(qp.z, cp.z, acc);
  float t = -2.0f * acc;
  t = t + qp.w;
  t = t + cp.w;
  return t;
}

__device__ __forceinline__ unsigned int pk_bf16(float a, float b) {
  __hip_bfloat162 h = __float22bfloat162_rn(make_float2(a, b));
  return *(unsigned int*)&h;
}

// packed fast-d for 8 candidates from ONE contiguous 128B blocked-SoA block
// [x0..7][y0..7][z0..7][w0..7]: 2x uniform 64B loads (single-stream sequential
// s_load pattern, R6/R8-proven) + v_pk_*_f32 math (2 cands/inst; SAME IEEE ops
// in SAME order as scalar chain -> bit-identical fast-d, R5-verified).
// 4-stream SoA is BLACKLISTED (R7: 1.5GB HBM explosion). Per-query overflow
// fallbacks are BLACKLISTED (R9: lane=query layout makes them block-wide).
__device__ __forceinline__ f32x8 dist8(
    float qw, float m2x, float m2y, float m2z,
    const f32x16* __restrict__ cs, int j)
{
  f32x16 lo = cs[2 * j];       // x0..7, y0..7
  f32x16 hi = cs[2 * j + 1];   // z0..7, w0..7
  f32x8 cx = __builtin_shufflevector(lo, lo, 0, 1, 2, 3, 4, 5, 6, 7);
  f32x8 cy = __builtin_shufflevector(lo, lo, 8, 9, 10, 11, 12, 13, 14, 15);
  f32x8 cz = __builtin_shufflevector(hi, hi, 0, 1, 2, 3, 4, 5, 6, 7);
  f32x8 cw = __builtin_shufflevector(hi, hi, 8, 9, 10, 11, 12, 13, 14, 15);
  f32x8 t = (f32x8)qw + cw;
  t = __builtin_elementwise_fma((f32x8)m2x, cx, t);
  t = __builtin_elementwise_fma((f32x8)m2y, cy, t);
  t = __builtin_elementwise_fma((f32x8)m2z, cz, t);
  return t;
}

// ---------------- prep: cpack AoS + cblk blocked-SoA + WbT
// (Q16 conversion moved into knn's idle tail waves — R11)
__global__ __launch_bounds__(256) void prep_kernel(
    const float* __restrict__ q_pos, const float* __restrict__ W,
    float4* __restrict__ cpack, float* __restrict__ cblk,
    unsigned short* __restrict__ WbT)
{
  int t = blockIdx.x * 256 + threadIdx.x;   // 0..131071
  {
    int k = t >> 9;
    int j = t & 511;
    float v;
    if (j < 256) {
      v = W[k * 256 + j];
    } else {
      int c = j - 256;
      v = W[(256 + k) * 256 + c] - W[k * 256 + c];
    }
    __hip_bfloat16 hb = __float2bfloat16(v);       // RNE
    WbT[(size_t)j * 256 + k] = *(unsigned short*)&hb;
  }
  if (t < BN_TOT) {
#pragma clang fp contract(off)
    float x = q_pos[3 * t + 0];
    float y = q_pos[3 * t + 1];
    float z = q_pos[3 * t + 2];
    float pxx = x * x;
    float pyy = y * y;
    float pzz = z * z;
    float s = pxx + pyy;
    s = s + pzz;
    cpack[t] = make_float4(x, y, z, s);
    // blocked-SoA: block (t>>3) holds [x0..7][y0..7][z0..7][w0..7]
    float* cb = cblk + ((size_t)(t >> 3) << 5) + (t & 7);
    cb[0] = x; cb[8] = y; cb[16] = z; cb[24] = s;
  }
}

// ---------------- knn (R8-proven structure, packed scans on blocked-SoA):
// presample hist -> per-query bin upper bound U -> scan1b: hist atomics
// predicated on d<edge(U) (bins<=U exact -> tight edge B* identical) ->
// scan2: collect d<edge into LDS -> 4-wave partial top-16 -> wave-0 merge.
// NEW (R11): waves 4-15, idle during phase 3a, run the Q->bf16 (Q16)
// conversion for the gemm (global-only work, no LDS interference; gemm runs
// strictly after knn on the stream).
// 1024-thr blocks: 64 queries (lane = query), 16 waves = 16 candidate slices.
__global__ __launch_bounds__(1024, 8) void knn_kernel(
    const float4* __restrict__ cpack, const float* __restrict__ cblk,
    int* __restrict__ idxout,
    const float* __restrict__ Q, unsigned short* __restrict__ Q16)
{
  __shared__ __align__(16) unsigned short cand[NSLICE * 64 * CAP]; // 64 KB; group-g region reused for (d,idx) lists
  __shared__ unsigned int hist[32][64];              // 8 KB bank-transposed shared hist
  __shared__ unsigned short scnt[NSLICE][64];        // per (slice,query) candidate count (2 KB)
  __shared__ float edge_s[64];
  __shared__ int ubnd[64];                           // per-query raw-bin upper bound (241+Bm)

  const int tid = threadIdx.x;
  const int l   = tid & 63;                        // query lane
  const int w   = __builtin_amdgcn_readfirstlane(tid >> 6);  // slice (wave-uniform)
  const int b   = blockIdx.y;
  const int q   = b * NPT + blockIdx.x * 64 + l;

  // zero shared histogram (2048 dwords / 1024 threads)
  ((unsigned int*)hist)[tid] = 0u;
  ((unsigned int*)hist)[tid + 1024] = 0u;
  __syncthreads();

  const float4 qp = cpack[q];
  const float m2x = -2.0f * qp.x, m2y = -2.0f * qp.y, m2z = -2.0f * qp.z;
  const float4* __restrict__ cb = cpack + b * NPT;
  const f32x16* __restrict__ cs = (const f32x16*)(cblk + (size_t)b * NPT * 4);
  const int j0 = (w * SLICE) >> 3;                 // 64 blocks of 8 per slice
  // hist row for raw-clamped bin r in [241,272]: fold -241 into the base.
  unsigned int* hb = (unsigned int*)((char*)&hist[0][0] - (241 << 8)) + l;

  // scan 1a (presample): first MINI candidates per slice, unpredicated atomics.
#pragma unroll 1
  for (int j = j0; j < j0 + MINI / 8; ++j) {
    f32x8 t = dist8(qp.w, m2x, m2y, m2z, cs, j);
#pragma unroll
    for (int u = 0; u < 8; ++u) {
      int r = __float_as_int(t[u]) >> 22;          // arith shift: d<=0 -> 241 after clamp
      r = min(max(r, 241), 272);
      atomicAdd(hb + (r << 6), 1u);                // bank = l&31: conflict-free
    }
  }
  __syncthreads();

  // per-query upper bound: Bm = bin of 16th smallest of the 512 samples.
  // sample subset of population => cum_full(Bm) >= 16 => true tight B* <= Bm.
  if (tid < 64) {
    int cum = 0, Bm = 31;
#pragma unroll 1
    for (int bb = 0; bb < 32; ++bb) {
      cum += (int)hist[bb][tid];
      if (cum >= KNN) { Bm = bb; break; }
    }
    ubnd[tid] = 241 + Bm;
  }
  __syncthreads();

  // scan 1b (rest of slice): atomics predicated on d < upper-edge(U).
  // (bin(d) <= U  <=>  d < edge(U): float bit-pattern monotone for d>=0;
  //  d<0 passes the compare and max() maps it to bin 241 — both sides agree.
  //  d < edge(U) <= edge(273) also bounds r <= 272, so no upper clamp needed.)
  // Bins <= U receive presample + remainder = EXACT full counts; bins > U are
  // undercounted but never reached by the cumsum (it stops at B* <= U).
  const int ub = ubnd[l];
  const float ubEdgef = __uint_as_float((unsigned)(ub + 1) << 22);
#pragma unroll 1
  for (int j = j0 + MINI / 8; j < j0 + SLICE / 8; ++j) {
    f32x8 t = dist8(qp.w, m2x, m2y, m2z, cs, j);
#pragma unroll
    for (int u = 0; u < 8; ++u) {
      if (t[u] < ubEdgef) {                        // rare
        int r = max(__float_as_int(t[u]) >> 22, 241);
        atomicAdd(hb + (r << 6), 1u);
      }
    }
  }
  __syncthreads();

  // cumsum -> bin B holding the 16th smallest; edge = upper(B) (R5/R7-proven)
  if (tid < 64) {
    int cum = 0, B = 31;
#pragma unroll 1
    for (int bb = 0; bb < 32; ++bb) {
      cum += (int)hist[bb][tid];
      if (cum >= KNN) { B = bb; break; }
    }
    edge_s[tid] = __uint_as_float((unsigned)(242 + B) << 22);
  }
  __syncthreads();

  // scan 2 (full): collect candidates with d < edge into LDS (ascending m)
  const float edgef = edge_s[l];
  unsigned int cnt = 0;
  unsigned short* mybuf = &cand[(w * 64 + l) * CAP];
#pragma unroll 1
  for (int j = j0; j < j0 + SLICE / 8; ++j) {
    f32x8 t = dist8(qp.w, m2x, m2y, m2z, cs, j);
#pragma unroll
    for (int u = 0; u < 8; ++u) {
      if (t[u] < edgef) {
        if (cnt < CAP) mybuf[cnt] = (unsigned short)((j << 3) + u);
        cnt++;
      }
    }
  }
  scnt[w][l] = (unsigned short)(cnt < (unsigned)CAP ? cnt : (unsigned)CAP);
  __syncthreads();

  // phase 3a: 4 groups (waves 0-3), group g owns slices [4g,4g+4).
  // Each lane (=query) builds an index-carrying sorted top-16 over its group's
  // candidates (stable insertion: ties keep earliest arrival = earliest index,
  // since slices and within-slice candidates ascend). Global top-16 is a
  // subset of the union of per-group top-16s. Lists written (d,idx)-packed,
  // lane-swizzled, into the group's own (fully consumed) cand region.
  if ((tid >> 6) < 4) {
    const int g = tid >> 6;
    const int nself = (q & (NPT - 1));
    float rd[16]; int ri[16];
#pragma unroll
    for (int j = 0; j < 16; ++j) { rd[j] = __builtin_inff(); ri[j] = nself; }
#pragma unroll 1
    for (int w2 = 4 * g; w2 < 4 * g + 4; ++w2) {
      int cw = (int)scnt[w2][l];
      for (int i = 0; i < cw; ++i) {
        int m = (int)cand[(w2 * 64 + l) * CAP + i];
        float d = dist2np(qp, cb[m]);
        if (d < rd[15]) {
          // insert at first j with d < rd[j] (strict: after equals = stable)
#pragma unroll
          for (int j = 15; j > 0; --j) {
            bool up = d < rd[j - 1];
            float nd = up ? rd[j - 1] : d;
            int   ni = up ? ri[j - 1] : m;
            if (d < rd[j]) { rd[j] = nd; ri[j] = ni; }
          }
          if (d < rd[0]) { rd[0] = d; ri[0] = m; }
        }
      }
    }
    float2* pls = (float2*)(cand + (size_t)g * 8192);   // 64q x 16 x 8B = 8KB of the 16KB region
#pragma unroll
    for (int j = 0; j < 16; ++j) {
      int pos = (j + l) & 15;                            // lane swizzle: spread banks
      pls[l * 16 + pos] = make_float2(rd[j], __int_as_float(ri[j]));
    }
  } else if (Q16) {
    // waves 4-15 (idle during the sort): Q -> bf16 conversion for the gemm.
    // Global-only work; gemm consumes Q16 strictly after knn completes.
    const float4* __restrict__ qs = (const float4*)Q;
    uint2* __restrict__ qd = (uint2*)Q16;
    const int bl  = blockIdx.y * 128 + blockIdx.x;       // 0..511
    const int wkr = bl * 768 + (tid - 256);              // 0..393215
#pragma unroll 1
    for (int i = wkr; i < BN_TOT * 64; i += 512 * 768) { // 2M float4s total
      float4 f = qs[i];
      qd[i] = make_uint2(pk_bf16(f.x, f.y), pk_bf16(f.z, f.w));
    }
  }
  __syncthreads();

  // phase 3b (wave 0, lane = query): 4-way merge of sorted lists, 16 steps.
  // Strict < keeps lowest group on ties => earliest global index (groups are
  // ascending slice ranges). +inf padding carries nself => default semantics.
  if (tid < 64) {
    const float2* pls0 = (const float2*)(cand);
    const float2* pls1 = (const float2*)(cand + 8192);
    const float2* pls2 = (const float2*)(cand + 16384);
    const float2* pls3 = (const float2*)(cand + 24576);
    int p0 = 0, p1 = 0, p2 = 0, p3 = 0;
    float2 h0 = pls0[l * 16 + (l & 15)];
    float2 h1 = pls1[l * 16 + (l & 15)];
    float2 h2 = pls2[l * 16 + (l & 15)];
    float2 h3 = pls3[l * 16 + (l & 15)];
#pragma unroll 1
    for (int s = 0; s < 16; ++s) {
      float bd = h0.x; int be = __float_as_int(h0.y); int bg = 0;
      if (h1.x < bd) { bd = h1.x; be = __float_as_int(h1.y); bg = 1; }
      if (h2.x < bd) { bd = h2.x; be = __float_as_int(h2.y); bg = 2; }
      if (h3.x < bd) { bd = h3.x; be = __float_as_int(h3.y); bg = 3; }
      idxout[(size_t)q * 16 + s] = be;
      p0 += (bg == 0); p1 += (bg == 1); p2 += (bg == 2); p3 += (bg == 3);
      int q0 = p0 < 16 ? p0 : 15;   // clamp: final (dead) reload stays in-bounds
      int q1 = p1 < 16 ? p1 : 15;
      int q2 = p2 < 16 ? p2 : 15;
      int q3 = p3 < 16 ? p3 : 15;
      h0 = pls0[l * 16 + ((q0 + l) & 15)];
      h1 = pls1[l * 16 + ((q1 + l) & 15)];
      h2 = pls2[l * 16 + ((q2 + l) & 15)];
      h3 = pls3[l * 16 + ((q3 + l) & 15)];
    }
  }
}

// ---------------- bf16 MFMA GEMM: Q[32768,256] x WbT[512,256]^T -> A16 bf16 (n<256), Qn=d_out f32 (n>=256,+bias)
// R8-proven single-buffer form (R10 double-buffer measured neutral).
// USEQ16: A-side staged from pre-converted bf16 Q16 (2 uint4 loads, no VALU
// conversion); else f32 loads + in-loop pk_bf16 (identical RNE values).
#define ASTRIDE 40   // LDS row stride in bf16 elems (80 B, 16B-aligned)
template<bool USEQ16>
__global__ __launch_bounds__(256) void gemm_kernel(
    const float* __restrict__ Q, const unsigned short* __restrict__ Q16,
    const unsigned short* __restrict__ WbT,
    const float* __restrict__ bias,
    unsigned short* __restrict__ A16, float* __restrict__ Qn)
{
  __shared__ __align__(16) unsigned short As[128 * ASTRIDE];
  __shared__ __align__(16) unsigned short Bs[128 * ASTRIDE];
  const int tid  = threadIdx.x;
  const int lane = tid & 63;
  const int wv   = tid >> 6;
  const int wr   = wv & 1, wc = wv >> 1;
  const int bid  = blockIdx.x;
  const int bm0  = (bid >> 2) * 128;     // grid linearized: 4 N-siblings adjacent
  const int bn0  = (bid & 3) * 128;
  const int srow = tid >> 1;
  const int skh  = tid & 1;
  const int quad = lane >> 4;
  const int l15  = lane & 15;
  const int soff = srow * ASTRIDE + skh * 16;

  f32x4 acc[4][4];
#pragma unroll
  for (int i = 0; i < 4; ++i)
#pragma unroll
    for (int j = 0; j < 4; ++j) acc[i][j] = (f32x4)0.0f;

  const float* ag = Q + (size_t)(bm0 + srow) * 256 + skh * 16;
  const unsigned short* ag16 = USEQ16 ? (Q16 + (size_t)(bm0 + srow) * 256 + skh * 16) : nullptr;
  const unsigned short* bg = WbT + (size_t)(bn0 + srow) * 256 + skh * 16;

  for (int k0 = 0; k0 < 256; k0 += 32) {
    uint4 a0, a1;
    if constexpr (USEQ16) {
      a0 = *(const uint4*)(ag16 + k0);
      a1 = *(const uint4*)(ag16 + k0 + 8);
    } else {
      float4 f0 = *(const float4*)(ag + k0);
      float4 f1 = *(const float4*)(ag + k0 + 4);
      float4 f2 = *(const float4*)(ag + k0 + 8);
      float4 f3 = *(const float4*)(ag + k0 + 12);
      a0.x = pk_bf16(f0.x, f0.y); a0.y = pk_bf16(f0.z, f0.w);
      a0.z = pk_bf16(f1.x, f1.y); a0.w = pk_bf16(f1.z, f1.w);
      a1.x = pk_bf16(f2.x, f2.y); a1.y = pk_bf16(f2.z, f2.w);
      a1.z = pk_bf16(f3.x, f3.y); a1.w = pk_bf16(f3.z, f3.w);
    }
    uint4 bv0 = *(const uint4*)(bg + k0);        // k-local [0,8)
    uint4 bv1 = *(const uint4*)(bg + k0 + 8);    // k-local [8,16)
    __syncthreads();
    *(uint4*)&As[soff] = a0;
    *(uint4*)&As[soff + 8] = a1;
    *(uint4*)&Bs[soff] = bv0;
    *(uint4*)&Bs[soff + 8] = bv1;
    __syncthreads();

    bf16x8 af[4], bf[4];
#pragma unroll
    for (int rt = 0; rt < 4; ++rt)
      af[rt] = *(const bf16x8*)&As[(wr * 64 + rt * 16 + l15) * ASTRIDE + quad * 8];
#pragma unroll
    for (int ct = 0; ct < 4; ++ct)
      bf[ct] = *(const bf16x8*)&Bs[(wc * 64 + ct * 16 + l15) * ASTRIDE + quad * 8];
#pragma unroll
    for (int rt = 0; rt < 4; ++rt)
#pragma unroll
      for (int ct = 0; ct < 4; ++ct)
        acc[rt][ct] = __builtin_amdgcn_mfma_f32_16x16x32_bf16(af[rt], bf[ct], acc[rt][ct], 0, 0, 0);
  }

  // epilogue: C/D layout col=lane&15, row=quad*4+reg (verified m89/m91)
  if (bn0 < 256) {
#pragma unroll
    for (int ct = 0; ct < 4; ++ct) {
      int col = bn0 + wc * 64 + ct * 16 + l15;
#pragma unroll
      for (int rt = 0; rt < 4; ++rt) {
        int rowb = bm0 + wr * 64 + rt * 16 + quad * 4;
#pragma unroll
        for (int r = 0; r < 4; ++r) {
          __hip_bfloat16 hb = __float2bfloat16(acc[rt][ct][r]);
          A16[(size_t)(rowb + r) * 256 + col] = *(unsigned short*)&hb;
        }
      }
    }
  } else {
#pragma unroll
    for (int ct = 0; ct < 4; ++ct) {
      int col = bn0 + wc * 64 + ct * 16 + l15 - 256;
      float bvl = bias[col];
#pragma unroll
      for (int rt = 0; rt < 4; ++rt) {
        int rowb = bm0 + wr * 64 + rt * 16 + quad * 4;
#pragma unroll
        for (int r = 0; r < 4; ++r)
          Qn[(size_t)(rowb + r) * 256 + col] = acc[rt][ct][r] + bvl;
      }
    }
  }
}

// ---------------- gather + leaky + max; Out holds Qn on entry, overwritten with result
// Monotonicity fusion (R11, bit-exact): max_j leaky(a_j + qn) ==
// leaky(max_j(a_j) + qn), since x+qn, 0.2*x and fmaxf are monotone and the
// rounded max is attained by one of the rounded values. Inner loop is now
// shift+max only (~2x fewer VALU); one add + leaky at the end.
// 4 queries/block, 64 lanes/query, 4 channels/lane: one neighbor row (512 B)
// per wave-instruction via ushort4.
__global__ __launch_bounds__(256) void gather_kernel(
    const unsigned short* __restrict__ A16, const int* __restrict__ idxout,
    float* __restrict__ Out)
{
  __shared__ int sidx[64];
  const int tid  = threadIdx.x;
  const int q0   = blockIdx.x * 4;
  const int sub  = tid >> 6;
  const int lane = tid & 63;
  const int q    = q0 + sub;
  const int b    = q >> 13;
  if (tid < 64) sidx[tid] = idxout[(size_t)q0 * 16 + tid];
  __syncthreads();
  const int c4 = lane * 4;
  float* op = Out + (size_t)q * 256 + c4;
  const float4 qn = *(const float4*)op;
  const unsigned short* __restrict__ Ab = A16 + (size_t)b * NPT * 256 + c4;
  const float NI = -__builtin_inff();
  f32x4 amax = {NI, NI, NI, NI};
#pragma unroll
  for (int j = 0; j < 16; ++j) {
    const ushort4 raw = *(const ushort4*)(Ab + (size_t)sidx[sub * 16 + j] * 256);
    f32x4 a;
    a[0] = __uint_as_float((unsigned)raw.x << 16);   // bf16 -> f32
    a[1] = __uint_as_float((unsigned)raw.y << 16);
    a[2] = __uint_as_float((unsigned)raw.z << 16);
    a[3] = __uint_as_float((unsigned)raw.w << 16);
    amax = __builtin_elementwise_max(amax, a);
  }
  float4 outv;
  {
    float h0 = amax[0] + qn.x;
    float h1 = amax[1] + qn.y;
    float h2 = amax[2] + qn.z;
    float h3 = amax[3] + qn.w;
    outv.x = fmaxf(h0, 0.2f * h0);   // leaky_relu(h, 0.2) == max(h, 0.2h)
    outv.y = fmaxf(h1, 0.2f * h1);
    outv.z = fmaxf(h2, 0.2f * h2);
    outv.w = fmaxf(h3, 0.2f * h3);
  }
  *(float4*)op = outv;
}

extern "C" void kernel_launch(void* const* d_in, const int* in_sizes, int n_in,
                              void* d_out, int out_size, void* d_ws, size_t ws_size,
                              hipStream_t stream)
{
  (void)in_sizes; (void)n_in; (void)out_size;
  const float* qf   = (const float*)d_in[0];
  const float* qpos = (const float*)d_in[1];
  const float* W    = (const float*)d_in[2];
  const float* bias = (const float*)d_in[3];

  char* ws = (char*)d_ws;
  size_t off = 0;
  auto alloc = [&](size_t bytes) {
    void* p = ws + off;
    off += (bytes + 255) & ~(size_t)255;
    return p;
  };
  float4* cpack       = (float4*)alloc((size_t)BN_TOT * sizeof(float4));       // 512 KB
  float* cblk         = (float*)alloc((size_t)BN_TOT * 4 * sizeof(float));     // 512 KB blocked-SoA
  unsigned short* WbT = (unsigned short*)alloc((size_t)512 * 256 * 2);         // 256 KB
  int* idxout         = (int*)alloc((size_t)BN_TOT * KNN * sizeof(int));       // 2 MB
  unsigned short* A16 = (unsigned short*)alloc((size_t)BN_TOT * CH * 2);       // 16 MB
  float* Out          = (float*)d_out;                                         // Qn then result

  // optional bf16 Q (gemm A-side prestage, converted inside knn's idle tail)
  unsigned short* Q16 = nullptr;
  if (ws_size >= off + (size_t)BN_TOT * CH * 2 + 256)
    Q16 = (unsigned short*)alloc((size_t)BN_TOT * CH * 2);                     // 16 MB

  prep_kernel<<<512, 256, 0, stream>>>(qpos, W, cpack, cblk, WbT);
  knn_kernel<<<dim3(128, BATCH), 1024, 0, stream>>>(cpack, cblk, idxout, qf, Q16);
  if (Q16)
    gemm_kernel<true><<<1024, 256, 0, stream>>>(qf, Q16, WbT, bias, A16, Out);
  else
    gemm_kernel<false><<<1024, 256, 0, stream>>>(qf, nullptr, WbT, bias, A16, Out);
  gather_kernel<<<BN_TOT / 4, 256, 0, stream>>>(A16, idxout, Out);
}